// Round 8
// baseline (165.382 us; speedup 1.0000x reference)
//
#include <hip/hip_runtime.h>
#include <math.h>

#define IC 512
#define KD 128
#define NC 32
#define DC 32
#define NTHR 1024

typedef __attribute__((ext_vector_type(8))) short bf16x8;
typedef __attribute__((ext_vector_type(4))) float f32x4;

__device__ __forceinline__ unsigned short f2bf(float f) {
    unsigned u = __builtin_bit_cast(unsigned, f);
    return (unsigned short)((u + 0x7fffu + ((u >> 16) & 1u)) >> 16);
}
#define MFMA(a, b, c) __builtin_amdgcn_mfma_f32_16x16x32_bf16(a, b, c, 0, 0, 0)

// LDS (62.6 KB total, 1 block/CU):
//  uni  : 8512 f32 (34048 B) — union: prologue f32 tile [64][133] | c_bf ushort [32][520]
//  s_s  : 32*128 f32 (16 KB) — s[n][k], rotation (k+4n)&31 within 32-lanes
//  wv_s : 32*136 ushort (8.5 KB) — wv bf16 [n][k]
//  v_s  : 32*33 f32 (4.2 KB)
__global__ __launch_bounds__(NTHR, 1)
void capsmfma(const float* __restrict__ x_g, const float* __restrict__ W_g,
              const float* __restrict__ b0_g, float* __restrict__ out_g,
              unsigned short* __restrict__ xT_g, unsigned short* __restrict__ xb_g)
{
    __shared__ __align__(16) float uni[8512];
    __shared__ __align__(16) float s_s[NC * KD];
    __shared__ __align__(16) unsigned short wv_s[NC * 136];
    __shared__ __align__(16) float v_s[NC * 33];

    const int t = threadIdx.x, b = blockIdx.x;
    const int w = t >> 6, l = t & 63, lm = l & 15, kg = (l >> 4) & 3;
    const float* __restrict__ xb = x_g + (size_t)b * IC * KD;
    unsigned short* __restrict__ xTb = xT_g + (size_t)b * KD * IC;   // [k][i] bf16
    unsigned short* __restrict__ xbb = xb_g + (size_t)b * IC * KD;   // [i][k] bf16
    unsigned short* c_bf = (unsigned short*)uni;                     // [32][520]

    // ---------------- prologue: build xT_bf[k][i] and x_bf[i][k] ----------------
    for (int c = 0; c < 8; ++c) {
        for (int rep = 0; rep < 2; ++rep) {
            int v = t + rep * NTHR;            // f4 idx 0..2047
            int i = v >> 5, kq = v & 31;
            float4 val = *(const float4*)(xb + (size_t)(c * 64 + i) * KD + (kq << 2));
            float* d = uni + i * 133 + (kq << 2);
            d[0] = val.x; d[1] = val.y; d[2] = val.z; d[3] = val.w;
        }
        __syncthreads();
        {   // transposed emit: thread (xk = t>>3, 8 i's)
            const int xk = t >> 3, i8 = (t & 7) * 8;
            unsigned q[4];
            #pragma unroll
            for (int j = 0; j < 4; ++j) {
                unsigned short lo = f2bf(uni[(i8 + 2 * j) * 133 + xk]);
                unsigned short hi = f2bf(uni[(i8 + 2 * j + 1) * 133 + xk]);
                q[j] = (unsigned)lo | ((unsigned)hi << 16);
            }
            float4 o = {__builtin_bit_cast(float, q[0]), __builtin_bit_cast(float, q[1]),
                        __builtin_bit_cast(float, q[2]), __builtin_bit_cast(float, q[3])};
            *(float4*)(xTb + (size_t)xk * IC + c * 64 + i8) = o;
        }
        {   // row-major bf16 emit: thread (i = t>>4, 8 k's)
            const int i = t >> 4, k0 = (t & 15) * 8;
            unsigned q[4];
            #pragma unroll
            for (int j = 0; j < 4; ++j) {
                unsigned short lo = f2bf(uni[i * 133 + k0 + 2 * j]);
                unsigned short hi = f2bf(uni[i * 133 + k0 + 2 * j + 1]);
                q[j] = (unsigned)lo | ((unsigned)hi << 16);
            }
            float4 o = {__builtin_bit_cast(float, q[0]), __builtin_bit_cast(float, q[1]),
                        __builtin_bit_cast(float, q[2]), __builtin_bit_cast(float, q[3])};
            *(float4*)(xbb + (size_t)(c * 64 + i) * KD + k0) = o;
        }
        __syncthreads();
    }

    // routing logits in MFMA-D layout: bb[mt][nt][reg] for
    // i = (2w+mt)*16 + kg*4 + reg,  n = lm + 16*nt
    float bb[2][2][4];
    #pragma unroll
    for (int mt = 0; mt < 2; ++mt)
        #pragma unroll
        for (int nt = 0; nt < 2; ++nt)
            #pragma unroll
            for (int reg = 0; reg < 4; ++reg)
                bb[mt][nt][reg] = b0_g[((size_t)(b * NC + lm + 16 * nt)) * IC +
                                       (2 * w + mt) * 16 + kg * 4 + reg];

    for (int r = 0; r < 3; ++r) {
        if (r > 0) {
            // ---- phase U: bb += x @ wv^T via MFMA (M=i, N=n, K=k), C seeded with bb ----
            f32x4 acc[2][2];
            #pragma unroll
            for (int mt = 0; mt < 2; ++mt)
                #pragma unroll
                for (int nt = 0; nt < 2; ++nt)
                    #pragma unroll
                    for (int reg = 0; reg < 4; ++reg) acc[mt][nt][reg] = bb[mt][nt][reg];
            for (int kt = 0; kt < 4; ++kt) {
                const int xk = kt * 32 + kg * 8;
                bf16x8 bfr0 = *(const bf16x8*)(const void*)(wv_s + (0 * 16 + lm) * 136 + xk);
                bf16x8 bfr1 = *(const bf16x8*)(const void*)(wv_s + (1 * 16 + lm) * 136 + xk);
                #pragma unroll
                for (int mt = 0; mt < 2; ++mt) {
                    const int i = (2 * w + mt) * 16 + lm;
                    float4 raw = *(const float4*)(xbb + (size_t)i * KD + xk);
                    bf16x8 afr = __builtin_bit_cast(bf16x8, raw);
                    acc[mt][0] = MFMA(afr, bfr0, acc[mt][0]);
                    acc[mt][1] = MFMA(afr, bfr1, acc[mt][1]);
                }
            }
            #pragma unroll
            for (int mt = 0; mt < 2; ++mt)
                #pragma unroll
                for (int nt = 0; nt < 2; ++nt)
                    #pragma unroll
                    for (int reg = 0; reg < 4; ++reg) bb[mt][nt][reg] = acc[mt][nt][reg];
        }

        // ---- softmax over n, in D-layout: reduce 2 regs + shfl over lm bits ----
        #pragma unroll
        for (int mt = 0; mt < 2; ++mt)
            #pragma unroll
            for (int reg = 0; reg < 4; ++reg) {
                float m = fmaxf(bb[mt][0][reg], bb[mt][1][reg]);
                m = fmaxf(m, __shfl_xor(m, 1)); m = fmaxf(m, __shfl_xor(m, 2));
                m = fmaxf(m, __shfl_xor(m, 4)); m = fmaxf(m, __shfl_xor(m, 8));
                float e0 = __expf(bb[mt][0][reg] - m);
                float e1 = __expf(bb[mt][1][reg] - m);
                float sum = e0 + e1;
                sum += __shfl_xor(sum, 1); sum += __shfl_xor(sum, 2);
                sum += __shfl_xor(sum, 4); sum += __shfl_xor(sum, 8);
                const float inv = 1.f / sum;
                const int i = (2 * w + mt) * 16 + kg * 4 + reg;
                c_bf[lm * 520 + i]        = f2bf(e0 * inv);
                c_bf[(lm + 16) * 520 + i] = f2bf(e1 * inv);
            }
        __syncthreads();

        // ---- phase C: s[n][xk] = sum_i c[n][i] x[i][xk]; MFMA M=n,N=xk,K=i ----
        {
            const int mt2 = w >> 3, xkt = w & 7;
            f32x4 acc2 = (f32x4){0.f, 0.f, 0.f, 0.f};
            for (int kt = 0; kt < 16; ++kt) {
                const int i0 = kt * 32 + kg * 8;
                float4 raw = *(const float4*)(xTb + (size_t)(xkt * 16 + lm) * IC + i0);
                bf16x8 bfr = __builtin_bit_cast(bf16x8, raw);
                bf16x8 afr = *(const bf16x8*)(const void*)(c_bf + (mt2 * 16 + lm) * 520 + i0);
                acc2 = MFMA(afr, bfr, acc2);
            }
            #pragma unroll
            for (int reg = 0; reg < 4; ++reg) {
                const int n = mt2 * 16 + kg * 4 + reg;
                const int xk = xkt * 16 + lm;
                s_s[n * KD + (xk & 96) + ((xk + 4 * n) & 31)] = acc2[reg];
            }
        }
        __syncthreads();

        // ---- phase W: s@W[n] + squash; thread (n = t>>5, d = t&31) ----
        {
            const int n = t >> 5, d = t & 31;
            const float* __restrict__ Wn = W_g + (size_t)n * KD * DC;
            float s = 0.f;
            #pragma unroll 8
            for (int k = 0; k < KD; ++k)
                s += s_s[n * KD + (k & 96) + ((k + 4 * n) & 31)] * Wn[k * DC + d];
            float sn = s * s;
            sn += __shfl_xor(sn, 1); sn += __shfl_xor(sn, 2);
            sn += __shfl_xor(sn, 4); sn += __shfl_xor(sn, 8); sn += __shfl_xor(sn, 16);
            const float fac = sn / ((1.f + sn) * (sqrtf(sn) + 1e-8f));
            const float vv = s * fac;
            if (r == 2) {
                out_g[((size_t)(b * NC + n)) * DC + d] = vv;
            } else {
                v_s[n * 33 + d] = vv;
            }
        }
        if (r < 2) {
            __syncthreads();
            // ---- wv[n][k] = W[n][k][:] . v[n][:]; thread (n = t>>5, 4 k's) ----
            {
                const int n = t >> 5, kq = t & 31;
                const float* __restrict__ Wn = W_g + (size_t)n * KD * DC;
                float a[4] = {0.f, 0.f, 0.f, 0.f};
                #pragma unroll 4
                for (int dd = 0; dd < DC; ++dd) {
                    const float vd = v_s[n * 33 + dd];
                    #pragma unroll
                    for (int j = 0; j < 4; ++j)
                        a[j] += Wn[(kq * 4 + j) * DC + dd] * vd;
                }
                ushort4 o;
                o.x = f2bf(a[0]); o.y = f2bf(a[1]); o.z = f2bf(a[2]); o.w = f2bf(a[3]);
                *(ushort4*)(wv_s + n * 136 + kq * 4) = o;
            }
            __syncthreads();   // wv_s ready for next r's phase U
        }
    }
}

extern "C" void kernel_launch(void* const* d_in, const int* in_sizes, int n_in,
                              void* d_out, int out_size, void* d_ws, size_t ws_size,
                              hipStream_t stream) {
    const float* x  = (const float*)d_in[0];
    const float* W  = (const float*)d_in[1];
    const float* b0 = (const float*)d_in[2];
    float* out = (float*)d_out;
    unsigned short* xT = (unsigned short*)d_ws;               // 8.4 MB bf16 x^T
    unsigned short* xbf = xT + (size_t)64 * KD * IC;          // 8.4 MB bf16 x row-major
    capsmfma<<<64, NTHR, 0, stream>>>(x, W, b0, out, xT, xbf);
}